// Round 2
// baseline (6056.857 us; speedup 1.0000x reference)
//
#include <hip/hip_runtime.h>
#include <math.h>

#define TT   2048
#define DD   1024
#define HH   16
#define HSS  64
#define EE   8
#define KTOP 2
#define LL   2
#define CAPP 512
#define NN   2048
#define DFF  4096
#define NK   (NN*KTOP)
#define HALF 32

// ---------------- embedding: x = tok_emb[ids] + pos_emb ----------------
__global__ __launch_bounds__(256) void embed_kernel(const int* __restrict__ ids,
                                                    const float* __restrict__ tok,
                                                    const float* __restrict__ pos,
                                                    float* __restrict__ x) {
  int t = blockIdx.x, tid = threadIdx.x;
  int id = ids[t];
  float4 a = ((const float4*)(tok + (long long)id * DD))[tid];
  float4 b = ((const float4*)(pos + (long long)t * DD))[tid];
  float4 r;
  r.x = a.x + b.x; r.y = a.y + b.y; r.z = a.z + b.z; r.w = a.w + b.w;
  ((float4*)(x + (long long)t * DD))[tid] = r;
}

// ---------------- RoPE sin/cos table (double precision) ----------------
__global__ __launch_bounds__(256) void sincos_kernel(float* __restrict__ st, float* __restrict__ ct) {
  int idx = blockIdx.x * 256 + threadIdx.x;      // T*HALF = 65536
  int t = idx >> 5, i = idx & 31;
  double div = exp(-(double)(2 * i) * (9.210340371976184 / 64.0)); // ln(10000)
  double a = (double)t * div;
  st[idx] = (float)sin(a);
  ct[idx] = (float)cos(a);
}

// ---------------- layernorm (row per block) ----------------
__global__ __launch_bounds__(256) void ln_kernel(const float* __restrict__ in, float* __restrict__ out,
                                                 const float* __restrict__ w, const float* __restrict__ b) {
  int row = blockIdx.x, tid = threadIdx.x;
  float4 v = ((const float4*)(in + (long long)row * DD))[tid];
  float s = v.x + v.y + v.z + v.w;
  float q = v.x * v.x + v.y * v.y + v.z * v.z + v.w * v.w;
#pragma unroll
  for (int off = 32; off > 0; off >>= 1) {
    s += __shfl_down(s, off);
    q += __shfl_down(q, off);
  }
  __shared__ float rs[4], rq[4];
  int wv = tid >> 6;
  if ((tid & 63) == 0) { rs[wv] = s; rq[wv] = q; }
  __syncthreads();
  float S = rs[0] + rs[1] + rs[2] + rs[3];
  float Q = rq[0] + rq[1] + rq[2] + rq[3];
  float mean = S * (1.0f / DD);
  float var = Q * (1.0f / DD) - mean * mean;
  float rstd = rsqrtf(var + 1e-5f);
  float4 wv4 = ((const float4*)w)[tid];
  float4 bv4 = ((const float4*)b)[tid];
  float4 r;
  r.x = (v.x - mean) * rstd * wv4.x + bv4.x;
  r.y = (v.y - mean) * rstd * wv4.y + bv4.y;
  r.z = (v.z - mean) * rstd * wv4.z + bv4.z;
  r.w = (v.w - mean) * rstd * wv4.w + bv4.w;
  ((float4*)(out + (long long)row * DD))[tid] = r;
}

// ---------------- fp32 tiled GEMM: C = A(MxK) * B(NxK)^T  [+bias][+relu][+res] ----------------
// flags: 1=bias, 2=relu, 4=residual-add. Batched over blockIdx.z with given strides.
// All M,N multiples of 128; K multiple of 16 (no edge handling).
__global__ __launch_bounds__(256) void gemm_kernel(
    const float* __restrict__ Aall, const float* __restrict__ Ball,
    const float* __restrict__ biasAll, const float* __restrict__ resAll,
    float* __restrict__ Call, int M, int Nn, int Kd, int flags,
    long long sA, long long sB, long long sBias, long long sC) {
  const float* A = Aall + (long long)blockIdx.z * sA;
  const float* B = Ball + (long long)blockIdx.z * sB;
  float* C = Call + (long long)blockIdx.z * sC;

  __shared__ float As[128 * 17];
  __shared__ float Bs[128 * 17];
  int tid = threadIdx.x;
  int tx = tid & 15, ty = tid >> 4;
  int bm = blockIdx.y * 128, bn = blockIdx.x * 128;
  int lrow = tid >> 2;
  int lk = (tid & 3) << 2;

  float acc[8][8];
#pragma unroll
  for (int i = 0; i < 8; i++)
#pragma unroll
    for (int j = 0; j < 8; j++) acc[i][j] = 0.f;

  const float* Arow0 = A + (long long)(bm + lrow) * Kd + lk;
  const float* Arow1 = A + (long long)(bm + lrow + 64) * Kd + lk;
  const float* Brow0 = B + (long long)(bn + lrow) * Kd + lk;
  const float* Brow1 = B + (long long)(bn + lrow + 64) * Kd + lk;

  for (int kb = 0; kb < Kd; kb += 16) {
    float4 a0 = *(const float4*)(Arow0 + kb);
    float4 a1 = *(const float4*)(Arow1 + kb);
    float4 b0 = *(const float4*)(Brow0 + kb);
    float4 b1 = *(const float4*)(Brow1 + kb);
    __syncthreads();
    As[lrow * 17 + lk + 0] = a0.x; As[lrow * 17 + lk + 1] = a0.y;
    As[lrow * 17 + lk + 2] = a0.z; As[lrow * 17 + lk + 3] = a0.w;
    As[(lrow + 64) * 17 + lk + 0] = a1.x; As[(lrow + 64) * 17 + lk + 1] = a1.y;
    As[(lrow + 64) * 17 + lk + 2] = a1.z; As[(lrow + 64) * 17 + lk + 3] = a1.w;
    Bs[lrow * 17 + lk + 0] = b0.x; Bs[lrow * 17 + lk + 1] = b0.y;
    Bs[lrow * 17 + lk + 2] = b0.z; Bs[lrow * 17 + lk + 3] = b0.w;
    Bs[(lrow + 64) * 17 + lk + 0] = b1.x; Bs[(lrow + 64) * 17 + lk + 1] = b1.y;
    Bs[(lrow + 64) * 17 + lk + 2] = b1.z; Bs[(lrow + 64) * 17 + lk + 3] = b1.w;
    __syncthreads();
#pragma unroll
    for (int k = 0; k < 16; k++) {
      float av[8], bv[8];
#pragma unroll
      for (int i = 0; i < 8; i++) av[i] = As[(ty + 16 * i) * 17 + k];
#pragma unroll
      for (int j = 0; j < 8; j++) bv[j] = Bs[(tx + 16 * j) * 17 + k];
#pragma unroll
      for (int i = 0; i < 8; i++)
#pragma unroll
        for (int j = 0; j < 8; j++) acc[i][j] = fmaf(av[i], bv[j], acc[i][j]);
    }
  }

  const float* bias = (flags & 1) ? (biasAll + (long long)blockIdx.z * sBias) : nullptr;
  const float* res = (flags & 4) ? (resAll + (long long)blockIdx.z * sC) : nullptr;
#pragma unroll
  for (int i = 0; i < 8; i++) {
    int row = bm + ty + 16 * i;
#pragma unroll
    for (int j = 0; j < 8; j++) {
      int col = bn + tx + 16 * j;
      float v = acc[i][j];
      if (flags & 1) v += bias[col];
      if (flags & 2) v = fmaxf(v, 0.f);
      if (flags & 4) v += res[(long long)row * Nn + col];
      C[(long long)row * Nn + col] = v;
    }
  }
}

// ---------------- RoPE in place on q,k inside qkv buffer ----------------
__global__ __launch_bounds__(256) void rope_kernel(float* __restrict__ qkv,
                                                   const float* __restrict__ st,
                                                   const float* __restrict__ ct) {
  int t = blockIdx.x, tid = threadIdx.x;
#pragma unroll
  for (int p = tid; p < HH * HALF; p += 256) {
    int h = p >> 5, i = p & 31;
    float s = st[t * HALF + i], c = ct[t * HALF + i];
    float* q = qkv + (long long)t * (3 * DD) + h * HSS;
    float q1 = q[i], q2 = q[i + HALF];
    q[i] = q1 * c - q2 * s;
    q[i + HALF] = q2 * c + q1 * s;
    float* k = q + DD;
    float k1 = k[i], k2 = k[i + HALF];
    k[i] = k1 * c - k2 * s;
    k[i + HALF] = k2 * c + k1 * s;
  }
}

// ---------------- flash attention: 1 thread = 1 q row ----------------
// grid (H, T/128), 128 threads. K/V 64-row tiles in LDS (broadcast reads).
// NOTE: output is written in [H, T, HS] (head-major) layout to reproduce the
// reference's av.transpose(0,2,1,3).reshape(B,T,D) — the (B,T,H,HS) tensor is
// transposed to (B,H,T,HS) and the FLAT memory of that is what hits out_w.
__global__ __launch_bounds__(128) void attn_kernel(const float* __restrict__ qkv,
                                                   float* __restrict__ attn) {
  int head = blockIdx.x;
  int qc = blockIdx.y;
  int tid = threadIdx.x;
  int qrow = qc * 128 + tid;
  int qdiv = qrow >> 6;  // wave-uniform (64 consecutive rows per wave)
  __shared__ float4 Ks[64 * 16];
  __shared__ float4 Vs[64 * 16];
  float4 q[16], o[16];
  const float4* qp = (const float4*)(qkv + (long long)qrow * (3 * DD) + head * HSS);
#pragma unroll
  for (int d = 0; d < 16; d++) { q[d] = qp[d]; o[d] = make_float4(0.f, 0.f, 0.f, 0.f); }
  float m = -INFINITY, l = 0.f;
  int nkt = qc * 2 + 2;
  for (int kt = 0; kt < nkt; kt++) {
    __syncthreads();
#pragma unroll
    for (int it = 0; it < 8; it++) {
      int fid = tid + it * 128;
      int krow = fid >> 4, d4 = fid & 15;
      const float* baseK = qkv + (long long)(kt * 64 + krow) * (3 * DD) + DD + head * HSS;
      Ks[fid] = *(const float4*)(baseK + d4 * 4);
      Vs[fid] = *(const float4*)(baseK + DD + d4 * 4);
    }
    __syncthreads();
    if (kt > qdiv) continue;  // wave-uniform skip of fully-masked tiles
    bool diag = (kt == qdiv);
#pragma unroll
    for (int g = 0; g < 4; g++) {
      float sbuf[16];
#pragma unroll
      for (int jj = 0; jj < 16; jj++) {
        int j = g * 16 + jj;
        float s = 0.f;
#pragma unroll
        for (int d = 0; d < 16; d++) {
          float4 kv = Ks[j * 16 + d];
          s = fmaf(q[d].x, kv.x, s); s = fmaf(q[d].y, kv.y, s);
          s = fmaf(q[d].z, kv.z, s); s = fmaf(q[d].w, kv.w, s);
        }
        s *= 0.125f;  // 1/sqrt(64)
        if (diag && (kt * 64 + j > qrow)) s = -1e30f;
        sbuf[jj] = s;
      }
      float gm = m;
#pragma unroll
      for (int jj = 0; jj < 16; jj++) gm = fmaxf(gm, sbuf[jj]);
      float scale = __expf(m - gm);
      m = gm;
      l *= scale;
#pragma unroll
      for (int d = 0; d < 16; d++) {
        o[d].x *= scale; o[d].y *= scale; o[d].z *= scale; o[d].w *= scale;
      }
#pragma unroll
      for (int jj = 0; jj < 16; jj++) {
        int j = g * 16 + jj;
        float p = __expf(sbuf[jj] - m);
        l += p;
#pragma unroll
        for (int d = 0; d < 16; d++) {
          float4 vv = Vs[j * 16 + d];
          o[d].x = fmaf(p, vv.x, o[d].x); o[d].y = fmaf(p, vv.y, o[d].y);
          o[d].z = fmaf(p, vv.z, o[d].z); o[d].w = fmaf(p, vv.w, o[d].w);
        }
      }
    }
  }
  float rl = 1.f / l;
  // head-major [H, T, HS] write (see note above)
  float4* op = (float4*)(attn + (long long)head * TT * HSS + (long long)qrow * HSS);
#pragma unroll
  for (int d = 0; d < 16; d++)
    op[d] = make_float4(o[d].x * rl, o[d].y * rl, o[d].z * rl, o[d].w * rl);
}

// ---------------- router: logits, noisy top-2, gates (double accumulation) ----------------
__global__ __launch_bounds__(64) void router_kernel(
    const float* __restrict__ y, const float* __restrict__ rw, const float* __restrict__ rb,
    const float* __restrict__ nw, const float* __restrict__ nb, const float* __restrict__ noise,
    int* __restrict__ slot_e, float* __restrict__ slot_g) {
  int n = blockIdx.x;
  int lane = threadIdx.x;
  double accr[EE], accn[EE];
#pragma unroll
  for (int e = 0; e < EE; e++) { accr[e] = 0.0; accn[e] = 0.0; }
  for (int j = 0; j < 16; j++) {
    float xv = y[(long long)n * DD + j * 64 + lane];
#pragma unroll
    for (int e = 0; e < EE; e++) {
      accr[e] += (double)xv * (double)rw[e * DD + j * 64 + lane];
      accn[e] += (double)xv * (double)nw[e * DD + j * 64 + lane];
    }
  }
#pragma unroll
  for (int e = 0; e < EE; e++) {
    for (int off = 32; off > 0; off >>= 1) {
      accr[e] += __shfl_down(accr[e], off);
      accn[e] += __shfl_down(accn[e], off);
    }
  }
  if (lane == 0) {
    float noisy[EE];
#pragma unroll
    for (int e = 0; e < EE; e++) {
      float lg = (float)accr[e] + rb[e];
      float nl = (float)accn[e] + nb[e];
      float sp = (nl > 0.f) ? (nl + log1pf(expf(-nl))) : log1pf(expf(nl));
      noisy[e] = lg + noise[n * EE + e] * sp;
    }
    int i0 = 0;
#pragma unroll
    for (int e = 1; e < EE; e++) if (noisy[e] > noisy[i0]) i0 = e;
    int i1 = -1;
#pragma unroll
    for (int e = 0; e < EE; e++) {
      if (e == i0) continue;
      if (i1 < 0 || noisy[e] > noisy[i1]) i1 = e;
    }
    float v0 = noisy[i0], v1 = noisy[i1];
    float e1 = __expf(v1 - v0);
    float inv = 1.f / (1.f + e1);
    slot_e[2 * n] = i0; slot_e[2 * n + 1] = i1;
    slot_g[2 * n] = inv; slot_g[2 * n + 1] = e1 * inv;
  }
}

// ---------------- deterministic rank scan (flattened N*K order) ----------------
__global__ __launch_bounds__(256) void scan_kernel(const int* __restrict__ slot_e,
                                                   int* __restrict__ slot_pos) {
  __shared__ int cnt[256 * EE];
  int tid = threadIdx.x;
  int base = tid * 16;  // 4096 / 256
  int c[EE];
#pragma unroll
  for (int e = 0; e < EE; e++) c[e] = 0;
  int loc[16];
  for (int i = 0; i < 16; i++) {
    int e = slot_e[base + i];
    loc[i] = e;
    c[e]++;
  }
#pragma unroll
  for (int e = 0; e < EE; e++) cnt[tid * EE + e] = c[e];
  __syncthreads();
  if (tid < EE) {
    int run = 0;
    for (int t2 = 0; t2 < 256; t2++) {
      int v = cnt[t2 * EE + tid];
      cnt[t2 * EE + tid] = run;
      run += v;
    }
  }
  __syncthreads();
  int run[EE];
#pragma unroll
  for (int e = 0; e < EE; e++) run[e] = cnt[tid * EE + e];
  for (int i = 0; i < 16; i++) {
    int e = loc[i];
    int r = run[e]++;
    slot_pos[base + i] = (r < CAPP) ? (e * CAPP + r) : -1;
  }
}

// ---------------- dispatch: disp[pos] = y[token] ----------------
__global__ __launch_bounds__(256) void dispatch_kernel(const float* __restrict__ y,
                                                       const int* __restrict__ slot_pos,
                                                       float* __restrict__ disp) {
  int i = blockIdx.x;
  int pos = slot_pos[i];
  if (pos < 0) return;
  int tok = i >> 1;
  ((float4*)(disp + (long long)pos * DD))[threadIdx.x] =
      ((const float4*)(y + (long long)tok * DD))[threadIdx.x];
}

// ---------------- combine: x += sum_k gate_k * eo[pos_k] ----------------
__global__ __launch_bounds__(256) void combine_kernel(float* __restrict__ x,
                                                      const float* __restrict__ eo,
                                                      const int* __restrict__ slot_pos,
                                                      const float* __restrict__ slot_g) {
  int n = blockIdx.x, tid = threadIdx.x;
  int p0 = slot_pos[2 * n], p1 = slot_pos[2 * n + 1];
  float g0 = slot_g[2 * n], g1 = slot_g[2 * n + 1];
  float4 v = ((float4*)(x + (long long)n * DD))[tid];
  if (p0 >= 0) {
    float4 e0 = ((const float4*)(eo + (long long)p0 * DD))[tid];
    v.x = fmaf(g0, e0.x, v.x); v.y = fmaf(g0, e0.y, v.y);
    v.z = fmaf(g0, e0.z, v.z); v.w = fmaf(g0, e0.w, v.w);
  }
  if (p1 >= 0) {
    float4 e1 = ((const float4*)(eo + (long long)p1 * DD))[tid];
    v.x = fmaf(g1, e1.x, v.x); v.y = fmaf(g1, e1.y, v.y);
    v.z = fmaf(g1, e1.z, v.z); v.w = fmaf(g1, e1.w, v.w);
  }
  ((float4*)(x + (long long)n * DD))[tid] = v;
}

extern "C" void kernel_launch(void* const* d_in, const int* in_sizes, int n_in,
                              void* d_out, int out_size, void* d_ws, size_t ws_size,
                              hipStream_t stream) {
  const int* input_ids = (const int*)d_in[0];
  const float* noise = (const float*)d_in[1];
  const float* tok_emb = (const float*)d_in[2];
  const float* pos_emb = (const float*)d_in[3];
  const float* ln1_w = (const float*)d_in[4];
  const float* ln1_b = (const float*)d_in[5];
  const float* ln2_w = (const float*)d_in[6];
  const float* ln2_b = (const float*)d_in[7];
  const float* qkv_w = (const float*)d_in[8];
  const float* out_w = (const float*)d_in[9];
  const float* router_w = (const float*)d_in[10];
  const float* router_b = (const float*)d_in[11];
  const float* noise_w = (const float*)d_in[12];
  const float* noise_b = (const float*)d_in[13];
  const float* e_w1 = (const float*)d_in[14];
  const float* e_b1 = (const float*)d_in[15];
  const float* e_w2 = (const float*)d_in[16];
  const float* e_b2 = (const float*)d_in[17];
  const float* lnf_w = (const float*)d_in[18];
  const float* lnf_b = (const float*)d_in[19];
  float* out = (float*)d_out;

  float* ws = (float*)d_ws;
  float* x = ws;                                    // N*D
  float* y = x + (size_t)NN * DD;                   // N*D
  float* qkv = y + (size_t)NN * DD;                 // N*3D
  float* attn = qkv + (size_t)NN * 3 * DD;          // N*D  ([H,T,HS] layout)
  float* disp = attn + (size_t)NN * DD;             // E*CAP*D
  float* hbuf = disp + (size_t)EE * CAPP * DD;      // E*CAP*4D
  float* eo = hbuf + (size_t)EE * CAPP * DFF;       // E*CAP*D
  float* sintab = eo + (size_t)EE * CAPP * DD;      // T*HALF
  float* costab = sintab + (size_t)TT * HALF;       // T*HALF
  int* slot_e = (int*)(costab + (size_t)TT * HALF); // NK
  int* slot_pos = slot_e + NK;                      // NK
  float* slot_g = (float*)(slot_pos + NK);          // NK

  embed_kernel<<<TT, 256, 0, stream>>>(input_ids, tok_emb, pos_emb, x);
  sincos_kernel<<<(TT * HALF) / 256, 256, 0, stream>>>(sintab, costab);

  for (int l = 0; l < LL; l++) {
    ln_kernel<<<NN, 256, 0, stream>>>(x, y, ln1_w + l * DD, ln1_b + l * DD);
    gemm_kernel<<<dim3(3 * DD / 128, NN / 128, 1), 256, 0, stream>>>(
        y, qkv_w + (size_t)l * 3 * DD * DD, nullptr, nullptr, qkv,
        NN, 3 * DD, DD, 0, 0, 0, 0, 0);
    rope_kernel<<<TT, 256, 0, stream>>>(qkv, sintab, costab);
    attn_kernel<<<dim3(HH, TT / 128), 128, 0, stream>>>(qkv, attn);
    gemm_kernel<<<dim3(DD / 128, NN / 128, 1), 256, 0, stream>>>(
        attn, out_w + (size_t)l * DD * DD, nullptr, x, x,
        NN, DD, DD, 4, 0, 0, 0, 0);
    ln_kernel<<<NN, 256, 0, stream>>>(x, y, ln2_w + l * DD, ln2_b + l * DD);
    router_kernel<<<NN, 64, 0, stream>>>(
        y, router_w + (size_t)l * EE * DD, router_b + l * EE,
        noise_w + (size_t)l * EE * DD, noise_b + l * EE,
        noise + (size_t)l * NN * EE, slot_e, slot_g);
    scan_kernel<<<1, 256, 0, stream>>>(slot_e, slot_pos);
    dispatch_kernel<<<NK, 256, 0, stream>>>(y, slot_pos, disp);
    gemm_kernel<<<dim3(DFF / 128, CAPP / 128, EE), 256, 0, stream>>>(
        disp, e_w1 + (size_t)l * EE * DFF * DD, e_b1 + (size_t)l * EE * DFF, nullptr, hbuf,
        CAPP, DFF, DD, 3,
        (long long)CAPP * DD, (long long)DFF * DD, DFF, (long long)CAPP * DFF);
    gemm_kernel<<<dim3(DD / 128, CAPP / 128, EE), 256, 0, stream>>>(
        hbuf, e_w2 + (size_t)l * EE * DD * DFF, e_b2 + (size_t)l * EE * DD, nullptr, eo,
        CAPP, DD, DFF, 1,
        (long long)CAPP * DFF, (long long)DD * DFF, DD, (long long)CAPP * DD);
    combine_kernel<<<NN, 256, 0, stream>>>(x, eo, slot_pos, slot_g);
  }
  ln_kernel<<<NN, 256, 0, stream>>>(x, out, lnf_w, lnf_b);
  (void)in_sizes; (void)n_in; (void)out_size; (void)ws_size;
}